// Round 19
// baseline (152.989 us; speedup 1.0000x reference)
//
#include <hip/hip_runtime.h>

// VQGAN VectorQuantizer forward — BM=64, 2 blocks/CU, e-register-pipelined.
// z: (32,256,32,32) f32, emb: (1024,256) f32.
// d_out (float): [0..8388607] z_q | [8388608] loss | [8388609..] indices.
//
// Numerics: replicate np-f32 quantized score s = fl(fl(A+B) - 2*dot).
// dot via 3 bf16 MFMA GEMMs (z1e1+z1e2+z2e1; exact 2-term RNE splits); the
// per-(row,col) accumulation chain is bit-identical to rounds 6-18 (all
// passed). R19 only moves WHEN e-fragments are loaded (one step earlier,
// into a second register buffer) — same addresses, same values. A =
// (A0+A1)+(A2+A3) partials (validated R16-R18). Gate THR=8e-5 (flip bound
// ~6.5e-5; R15-R18 passed). Gated rows -> k_refine, BIT-EXACT R3 chain over
// candidate chunks. Loss = 1.25 * mean best score. z_q written in-kernel.

#define WS_B 0            // [1024]   B_k
#define WS_A 1024         // [4][32768] A quarter-partials
#define WS_PV 132096      // [16][32768] per-chunk best score
#define WS_E1 656384      // 262144 ushorts (e1 tiles)
#define WS_E2 787456      // 262144 ushorts (e2 tiles)
#define WS_LIST 918528    // [32768] int refine rows
#define WS_CNT 951296     // int refine count
#define WS_Z1T 951304     // fused mode: 2x 8388608 ushorts (z1t,z2t)
#define WS_FUSED_BYTES ((size_t)(WS_Z1T + 8388608) * 4)

#define DDIM 256
#define LOSS_OFF 8388608
#define IDX_OFF 8388609
#define Z2T_OFF 8388608   // ushort offset of z2t from z1t base
#define REFINE_THR 8e-5f

typedef __attribute__((ext_vector_type(8))) short bf16x8;
typedef __attribute__((ext_vector_type(4))) float f32x4;
typedef __attribute__((ext_vector_type(8))) ushort u16x8;

__device__ __forceinline__ ushort bf16_rne(float x) {
  unsigned u = __float_as_uint(x);
  return (ushort)((u + 0x7FFFu + ((u >> 16) & 1u)) >> 16);
}
__device__ __forceinline__ float bf16f(ushort h) {
  return __uint_as_float(((unsigned)h) << 16);
}
__device__ __forceinline__ void gld16(void* l, const void* g) {
  __builtin_amdgcn_global_load_lds(
      (const __attribute__((address_space(1))) unsigned int*)g,
      (__attribute__((address_space(3))) unsigned int*)l, 16, 0, 0);
}

// ---------------- A: prep. blocks 0..1023 = z (rt,quarter), 1024..1027 = e --
__global__ __launch_bounds__(256) void k_prep(const float* __restrict__ z,
                                              const float* __restrict__ emb,
                                              ushort* __restrict__ zt,
                                              float* __restrict__ ws,
                                              float* __restrict__ out) {
  __shared__ float lt[64][132];
  __shared__ float sq[128];
  const int tid = threadIdx.x;
  if (blockIdx.x >= 1024) {
    const int k = (blockIdx.x - 1024) * 256 + tid;   // 0..1023
    if (k == 0) { out[LOSS_OFF] = 0.0f; ((int*)ws)[WS_CNT] = 0; }
    const int ct = k >> 8, n = k & 255;
    const float* er = emb + k * DDIM;
    ushort* e1t = (ushort*)(ws + WS_E1);
    ushort* e2t = (ushort*)(ws + WS_E2);
    float bsum = 0.f;
    for (int s = 0; s < 8; ++s) {
#pragma unroll
      for (int kq = 0; kq < 4; ++kq) {
        const float4 v0 = *(const float4*)(er + s * 32 + kq * 8);
        const float4 v1 = *(const float4*)(er + s * 32 + kq * 8 + 4);
        const float v[8] = {v0.x, v0.y, v0.z, v0.w, v1.x, v1.y, v1.z, v1.w};
        u16x8 h, l;
#pragma unroll
        for (int j = 0; j < 8; ++j) {
          bsum = fmaf(v[j], v[j], bsum);
          h[j] = bf16_rne(v[j]);
          l[j] = bf16_rne(v[j] - bf16f(h[j]));
        }
        const int off = ct * 65536 + s * 8192 + kq * 2048 + n * 8;
        *(u16x8*)(e1t + off) = h;
        *(u16x8*)(e2t + off) = l;
      }
    }
    ws[WS_B + k] = bsum;
    return;
  }
  const int rt = blockIdx.x >> 2;
  const int qp = blockIdx.x & 3;
  const int b = rt >> 3;
  const int hw0 = (rt & 7) << 7;
  ushort* z1t = zt;
  ushort* z2t = zt + Z2T_OFF;
  const int m = tid & 127, half = tid >> 7;
  const int lc = tid >> 2, lq = tid & 3;
  float as[4] = {0.f, 0.f, 0.f, 0.f};
  {
    const float* src = z + b * 262144 + ((qp << 6) + lc) * 1024 + hw0 + (lq << 5);
#pragma unroll
    for (int i = 0; i < 8; ++i)
      *(float4*)&lt[lc][(lq << 5) + (i << 2)] = *(const float4*)(src + (i << 2));
    __syncthreads();
    const int s = (qp << 1) + half;
#pragma unroll
    for (int kq = 0; kq < 4; ++kq) {
      u16x8 h, l;
#pragma unroll
      for (int j = 0; j < 8; ++j) {
        const float v = lt[(half << 5) + (kq << 3) + j][m];
        as[j & 3] = fmaf(v, v, as[j & 3]);
        h[j] = bf16_rne(v);
        l[j] = bf16_rne(v - bf16f(h[j]));
      }
      const int off = rt * 32768 + ((s << 2) + kq) * 1024 + (m << 3);
      *(u16x8*)(z1t + off) = h;
      *(u16x8*)(z2t + off) = l;
    }
    __syncthreads();
  }
  const float asum = (as[0] + as[1]) + (as[2] + as[3]);
  if (half) sq[m] = asum;
  __syncthreads();
  if (!half) ws[WS_A + qp * 32768 + rt * 128 + m] = asum + sq[m];
}

// ---------------- B: MFMA score — BM=64, e reg-pipelined, 2 blocks/CU -------
// 512 thr (8 waves 2x4; wave = 32 rows x 64 cols), 4 ct-strips x 8 K-steps.
// z dbuf 16 KB via gld16 (vmcnt(1) ledger); e fragments double-buffered in
// REGISTERS, loaded one step ahead (L2 latency hidden under MFMA). The q-loop
// is hand-unrolled x2 so all e-buffer indices are compile-time (rule #20).
__global__ __launch_bounds__(512, 4) void k_score(const ushort* __restrict__ zt,
                                                  const float* __restrict__ emb,
                                                  float* out,
                                                  float* __restrict__ ws,
                                                  int fused) {
  __shared__ __align__(16) char smem[33312];
  ushort* zl = (ushort*)smem;                 // dbuf 2 x 4096 ushorts (16 KB)
  float* Bs = (float*)(smem + 16384);         // 1024 f
  float* pvs = (float*)(smem + 20480);        // [16][64]
  float* sm2 = (float*)(smem + 33024);        // 8 f
  int* idxs = (int*)(smem + 33056);           // 64 ints
  const int tid = threadIdx.x;
  const int bid = blockIdx.x;                 // 0..511
  const int rt = ((bid >> 4) << 3) | (bid & 7);    // pair halves share an XCD
  const int mh = ((bid >> 3) & 1) << 6;            // m-half within rt tile
  const int row0 = (rt << 7) + mh;                 // 64 rows
  const ushort* z1t = zt;
  const ushort* z2t = zt + Z2T_OFF;
  const ushort* e1t = (const ushort*)(ws + WS_E1);
  const ushort* e2t = (const ushort*)(ws + WS_E2);
  const int w = tid >> 6, L = tid & 63;
  const int l15 = L & 15, kq = L >> 4;
  const int wr = w >> 2, wc = w & 3;          // 2 x 4 wave grid

  Bs[tid] = ws[WS_B + tid];
  Bs[tid + 512] = ws[WS_B + tid + 512];
  float Av[2][4];
#pragma unroll
  for (int mi = 0; mi < 2; ++mi) {
    const int base = row0 + (wr << 5) + (mi << 4) + (kq << 2);
    const float4 a0 = *(const float4*)(ws + WS_A + base);
    const float4 a1 = *(const float4*)(ws + WS_A + 32768 + base);
    const float4 a2 = *(const float4*)(ws + WS_A + 65536 + base);
    const float4 a3 = *(const float4*)(ws + WS_A + 98304 + base);
    Av[mi][0] = (a0.x + a1.x) + (a2.x + a3.x);
    Av[mi][1] = (a0.y + a1.y) + (a2.y + a3.y);
    Av[mi][2] = (a0.z + a1.z) + (a2.z + a3.z);
    Av[mi][3] = (a0.w + a1.w) + (a2.w + a3.w);
  }
  asm volatile("s_waitcnt vmcnt(0)" ::: "memory");
  __builtin_amdgcn_sched_barrier(0);
  __syncthreads();

  // z staging: wave w owns one 1KB slab per step: kq=w&3, array z1 (w<4)/z2
  const ushort* zsrc = (w < 4 ? z1t : z2t) + rt * 32768 + ((w & 3) << 10)
                       + (mh << 3) + (L << 3);
  ushort* zdst0 = zl + ((w & 3) << 9) + ((w >> 2) << 11);
  auto stage = [&](int q, int bf) {
    gld16(zdst0 + (bf << 12), zsrc + ((q & 7) << 12));
  };
  // e fragment addressing (global, fragment-ordered); double reg buffer
  const int ebase_th = (kq << 11) + (((wc << 6) + l15) << 3);
  bf16x8 b1[2][4], b2[2][4];
  auto eload = [&](int q, int buf) {   // buf must be compile-time at call site
    const int ct = q >> 3, s = q & 7;
    const ushort* e1p = e1t + (ct << 16) + (s << 13) + ebase_th;
    const ushort* e2p = e2t + (ct << 16) + (s << 13) + ebase_th;
#pragma unroll
    for (int nj = 0; nj < 4; ++nj) {
      b1[buf][nj] = *(const bf16x8*)(e1p + (nj << 7));
      b2[buf][nj] = *(const bf16x8*)(e2p + (nj << 7));
    }
  };

  f32x4 acc[2][4];
  float v1[2][4], v2[2][4];
  int i1[2][4];
#pragma unroll
  for (int mi = 0; mi < 2; ++mi)
#pragma unroll
    for (int r = 0; r < 4; ++r) {
      acc[mi][r] = (f32x4){0.f, 0.f, 0.f, 0.f};
      v1[mi][r] = 3.0e38f; v2[mi][r] = 3.0e38f; i1[mi][r] = 0;
    }

  stage(0, 0);    // z0
  eload(0, 0);    // e0 x8
  stage(1, 1);    // z1   -> outstanding [z0, e0(8), z1]

  auto body = [&](int q, int cur, bool last) {
    // ledger: outstanding = [z(q), e(q)x8, z(q+1)] -> vmcnt(1) drains z(q)+e(q)
    if (!last) asm volatile("s_waitcnt vmcnt(1)" ::: "memory");
    else       asm volatile("s_waitcnt vmcnt(0)" ::: "memory");
    __builtin_amdgcn_sched_barrier(0);
    __builtin_amdgcn_s_barrier();
    __builtin_amdgcn_sched_barrier(0);
    const ushort* lb = zl + (cur << 12);
    bf16x8 a1[2], a2[2];
#pragma unroll
    for (int mi = 0; mi < 2; ++mi) {
      const int off = (kq << 9) + (((wr << 5) + (mi << 4) + l15) << 3);
      a1[mi] = *(const bf16x8*)&lb[off];
      a2[mi] = *(const bf16x8*)&lb[2048 + off];
    }
    asm volatile("s_waitcnt lgkmcnt(0)" ::: "memory");
    __builtin_amdgcn_sched_barrier(0);
    __builtin_amdgcn_s_barrier();
    __builtin_amdgcn_sched_barrier(0);
    if (!last) eload(q + 1, cur ^ 1);   // e(q+1) -> other reg buffer
    if (q < 30) stage(q + 2, cur);      // z(q+2) -> freed LDS buffer
    __builtin_amdgcn_s_setprio(1);
#pragma unroll
    for (int mi = 0; mi < 2; ++mi)
#pragma unroll
      for (int nj = 0; nj < 4; ++nj) {
        acc[mi][nj] = __builtin_amdgcn_mfma_f32_16x16x32_bf16(a2[mi], b1[cur][nj], acc[mi][nj], 0, 0, 0);
        acc[mi][nj] = __builtin_amdgcn_mfma_f32_16x16x32_bf16(a1[mi], b2[cur][nj], acc[mi][nj], 0, 0, 0);
        acc[mi][nj] = __builtin_amdgcn_mfma_f32_16x16x32_bf16(a1[mi], b1[cur][nj], acc[mi][nj], 0, 0, 0);
      }
    __builtin_amdgcn_s_setprio(0);
    if ((q & 7) == 7) {   // strip boundary: fold scores + chunk minima
      const int ct = q >> 3;
      float bb[4];
#pragma unroll
      for (int nj = 0; nj < 4; ++nj)
        bb[nj] = Bs[(ct << 8) + (wc << 6) + (nj << 4) + l15];
      float cm[2][4];
#pragma unroll
      for (int mi = 0; mi < 2; ++mi)
#pragma unroll
        for (int r = 0; r < 4; ++r) cm[mi][r] = 3.0e38f;
#pragma unroll
      for (int mi = 0; mi < 2; ++mi)
#pragma unroll
        for (int nj = 0; nj < 4; ++nj) {
          const int kg = (ct << 8) + (wc << 6) + (nj << 4) + l15;
#pragma unroll
          for (int r = 0; r < 4; ++r) {
            const float sc = fmaf(-2.0f, acc[mi][nj][r], Av[mi][r] + bb[nj]);
            if (sc < v1[mi][r]) { v2[mi][r] = v1[mi][r]; v1[mi][r] = sc; i1[mi][r] = kg; }
            else if (sc < v2[mi][r]) v2[mi][r] = sc;
            cm[mi][r] = fminf(cm[mi][r], sc);
          }
          acc[mi][nj] = (f32x4){0.f, 0.f, 0.f, 0.f};
        }
#pragma unroll
      for (int mi = 0; mi < 2; ++mi)
#pragma unroll
        for (int r = 0; r < 4; ++r) {
          float cv = cm[mi][r];
#pragma unroll
          for (int o = 1; o < 16; o <<= 1) cv = fminf(cv, __shfl_xor(cv, o));
          if (l15 == 0) {
            const int rowl = (wr << 5) + (mi << 4) + (kq << 2) + r;
            pvs[((ct << 2) | wc) * 64 + rowl] = cv;
          }
        }
    }
  };

  // hand-unrolled x2: e-buffer index compile-time at every call (rule #20)
  for (int qp = 0; qp < 15; ++qp) {
    body(2 * qp, 0, false);
    body(2 * qp + 1, 1, false);
  }
  body(30, 0, false);
  body(31, 1, true);

  // cross-l15 reduce of global top-2
#pragma unroll
  for (int mi = 0; mi < 2; ++mi)
#pragma unroll
    for (int r = 0; r < 4; ++r) {
      float a = v1[mi][r], bb = v2[mi][r];
      int ii = i1[mi][r];
#pragma unroll
      for (int o = 1; o < 16; o <<= 1) {
        const float oa = __shfl_xor(a, o);
        const float ob = __shfl_xor(bb, o);
        const int oi = __shfl_xor(ii, o);
        bb = fminf(fminf(bb, ob), fmaxf(a, oa));
        if (oa < a || (oa == a && oi < ii)) { a = oa; ii = oi; }
      }
      v1[mi][r] = a; v2[mi][r] = bb; i1[mi][r] = ii;
    }

  __syncthreads();
  // flush chunk minima to ws
  for (int i = tid; i < 1024; i += 512) {
    const int c = i >> 6, rl = i & 63;
    ws[WS_PV + (c << 15) + row0 + rl] = pvs[i];
  }
  float* red = (float*)smem;   // [4 wc][64 rows][3] = 3 KB (z dbuf dead)
  if (l15 == 0) {
#pragma unroll
    for (int mi = 0; mi < 2; ++mi)
#pragma unroll
      for (int r = 0; r < 4; ++r) {
        const int rl = (wr << 5) + (mi << 4) + (kq << 2) + r;
        const int b3 = (wc * 64 + rl) * 3;
        red[b3] = v1[mi][r];
        red[b3 + 1] = v2[mi][r];
        red[b3 + 2] = (float)i1[mi][r];
      }
  }
  __syncthreads();
  float losss = 0.f;
  if (tid < 64) {
    float fv1 = 3.0e38f, fv2 = 3.0e38f;
    int fi = 0;
#pragma unroll
    for (int c = 0; c < 4; ++c) {
      const int b3 = (c * 64 + tid) * 3;
      const float a1 = red[b3], a2 = red[b3 + 1];
      const int ai = (int)red[b3 + 2];
      if (a1 < fv1 || (a1 == fv1 && ai < fi)) { fv2 = fminf(fv1, a2); fv1 = a1; fi = ai; }
      else fv2 = fminf(fv2, a1);
    }
    const int row = row0 + tid;
    out[IDX_OFF + row] = (float)fi;
    idxs[tid] = fi;
    if (fv2 - fv1 < REFINE_THR) {
      const int slot = atomicAdd((int*)ws + WS_CNT, 1);
      ((int*)ws)[WS_LIST + slot] = row;
    }
    losss = fv1;
  }
#pragma unroll
  for (int o = 32; o; o >>= 1) losss += __shfl_down(losss, o);
  if ((tid & 63) == 0) sm2[tid >> 6] = losss;
  __syncthreads();
  if (tid == 0) {
    float t = 0.f;
#pragma unroll
    for (int i = 0; i < 8; ++i) t += sm2[i];
    atomicAdd(out + LOSS_OFF, t * (1.25f / 8388608.0f));
  }

  // ---- fused tail: z_q via LDS transpose, 2 col-half passes ----
  if (fused) {
    float* lt2 = (float*)smem;   // [64][129] f32 = 33024 B
    const int b = row0 >> 10;
    const int hw0 = row0 & 1023;
    for (int ch = 0; ch < 2; ++ch) {
      __syncthreads();
      {
        const int r = tid >> 3, seg = tid & 7;
        const float* er = emb + idxs[r] * DDIM + (ch << 7);
        float* dst = lt2 + r * 129;
#pragma unroll
        for (int i = 0; i < 4; ++i) {
          const int c = (seg << 2) + (i << 5);
          const float4 v = *(const float4*)(er + c);
          dst[c] = v.x; dst[c + 1] = v.y; dst[c + 2] = v.z; dst[c + 3] = v.w;
        }
      }
      __syncthreads();
      {
        const int c = tid >> 2;
        const int r0 = (tid & 3) << 4;
        float* dsto = out + b * 262144 + ((ch << 7) + c) * 1024 + hw0 + r0;
#pragma unroll
        for (int i = 0; i < 16; i += 4) {
          float4 v;
          v.x = lt2[(r0 + i + 0) * 129 + c];
          v.y = lt2[(r0 + i + 1) * 129 + c];
          v.z = lt2[(r0 + i + 2) * 129 + c];
          v.w = lt2[(r0 + i + 3) * 129 + c];
          *(float4*)(dsto + i) = v;
        }
      }
    }
  }
}

// ---------------- B3: exact re-solve, candidate chunks, grid-stride ---------
__global__ __launch_bounds__(256) void k_refine(const float* __restrict__ z,
                                                const float* __restrict__ emb,
                                                const float* __restrict__ ws,
                                                float* __restrict__ out,
                                                int fused) {
  __shared__ float zs[4][256];
  const int tid = threadIdx.x;
  const int w = tid >> 6, L = tid & 63;
  const int wg = blockIdx.x * 4 + w;
  const int cnt = ((const int*)ws)[WS_CNT];
  for (int e = wg; e < cnt; e += 1024) {
    const int row = ((const int*)ws)[WS_LIST + e];
    const int b = row >> 10, hw = row & 1023;
#pragma unroll
    for (int q = 0; q < 4; ++q)
      zs[w][(q << 6) + L] = z[b * 262144 + (((q << 6) + L) << 10) + hw];
    asm volatile("s_waitcnt lgkmcnt(0)" ::: "memory");
    float v1c = (L < 16) ? ws[WS_PV + (L << 15) + row] : 3.0e38f;
    float v1 = v1c;
#pragma unroll
    for (int o = 1; o < 64; o <<= 1) v1 = fminf(v1, __shfl_xor(v1, o));
    const float A = (ws[WS_A + row] + ws[WS_A + 32768 + row]) +
                    (ws[WS_A + 65536 + row] + ws[WS_A + 98304 + row]);
    float bv = 3.0e38f;
    int bk = 0;
    for (int tc = 0; tc < 16; ++tc) {
      const float bc = __shfl(v1c, tc);
      if (bc <= v1 + REFINE_THR) {
        const int k = (tc << 6) + L;
        const float* er = emb + k * DDIM;
        float s = 0.f;
        for (int d = 0; d < DDIM; ++d) s = fmaf(zs[w][d], er[d], s);  // R3 chain
        const float sc = fmaf(-2.0f, s, A + ws[WS_B + k]);
        if (sc < bv) { bv = sc; bk = k; }
      }
    }
#pragma unroll
    for (int o = 1; o < 64; o <<= 1) {
      const float ov = __shfl_xor(bv, o);
      const int ok = __shfl_xor(bk, o);
      if (ov < bv || (ov == bv && ok < bk)) { bv = ov; bk = ok; }
    }
    if (L == 0) out[IDX_OFF + row] = (float)bk;
    if (fused) {
#pragma unroll
      for (int ci = 0; ci < 4; ++ci) {
        const int c = (ci << 6) + L;
        out[b * 262144 + c * 1024 + hw] = emb[bk * DDIM + c];
      }
    }
  }
}

// ---------------- C: z_q gather (legacy path only) ----------------
__global__ __launch_bounds__(256) void k_gather(const float* __restrict__ emb,
                                                float* __restrict__ out) {
  const int tid = threadIdx.x;
  const int e0 = (blockIdx.x * 256 + tid) * 16;
  const int b = e0 >> 18;
  const int c = (e0 >> 10) & 255;
  const int n0 = (b << 10) + (e0 & 1023);
#pragma unroll
  for (int g = 0; g < 4; ++g) {
    float q[4];
#pragma unroll
    for (int j = 0; j < 4; ++j) {
      const int id = (int)(out[IDX_OFF + n0 + g * 4 + j] + 0.5f);
      q[j] = emb[id * DDIM + c];
    }
    const float4 qv = {q[0], q[1], q[2], q[3]};
    *(float4*)(out + e0 + g * 4) = qv;
  }
}

extern "C" void kernel_launch(void* const* d_in, const int* in_sizes, int n_in,
                              void* d_out, int out_size, void* d_ws, size_t ws_size,
                              hipStream_t stream) {
  const float* z = (const float*)d_in[0];
  const float* emb = (const float*)d_in[1];
  float* out = (float*)d_out;
  float* ws = (float*)d_ws;
  const int fused = (ws_size >= WS_FUSED_BYTES) ? 1 : 0;
  ushort* zt = fused ? (ushort*)(ws + WS_Z1T) : (ushort*)out;

  k_prep<<<1028, 256, 0, stream>>>(z, emb, zt, ws, out);
  k_score<<<512, 512, 0, stream>>>(zt, emb, out, ws, fused);
  k_refine<<<256, 256, 0, stream>>>(z, emb, ws, out, fused);
  if (!fused) k_gather<<<2048, 256, 0, stream>>>(emb, out);
}

// Round 20
// 123.550 us; speedup vs baseline: 1.2383x; 1.2383x over previous
//
#include <hip/hip_runtime.h>

// VQGAN VectorQuantizer forward — R18 + early e-load issue (single buffer).
// z: (32,256,32,32) f32, emb: (1024,256) f32.
// d_out (float): [0..8388607] z_q | [8388608] loss | [8388609..] indices.
//
// Numerics: replicate np-f32 quantized score s = fl(fl(A+B) - 2*dot).
// dot via 3 bf16 MFMA GEMMs (z1e1+z1e2+z2e1; exact 2-term RNE splits); the
// per-(row,col) accumulation chain is bit-identical to rounds 6-18 (all
// passed). R20 only moves WHERE in the step the e-fragment loads are issued
// (after barrier 1 instead of barrier 2) — same addresses, same values,
// single register buffer (R19's double buffer spilled: WRITE_SIZE 35->117MB).
// A = (A0+A1)+(A2+A3) partials (validated R16-R18). Gate THR=8e-5 (flip
// bound ~6.5e-5; R15-R18 passed). Gated rows -> k_refine, BIT-EXACT R3 chain
// over candidate chunks. Loss = 1.25 * mean best score. z_q written in-kernel.

#define WS_B 0            // [1024]   B_k
#define WS_A 1024         // [4][32768] A quarter-partials
#define WS_PV 132096      // [16][32768] per-chunk best score
#define WS_E1 656384      // 262144 ushorts (e1 tiles)
#define WS_E2 787456      // 262144 ushorts (e2 tiles)
#define WS_LIST 918528    // [32768] int refine rows
#define WS_CNT 951296     // int refine count
#define WS_Z1T 951304     // fused mode: 2x 8388608 ushorts (z1t,z2t)
#define WS_FUSED_BYTES ((size_t)(WS_Z1T + 8388608) * 4)

#define DDIM 256
#define LOSS_OFF 8388608
#define IDX_OFF 8388609
#define Z2T_OFF 8388608   // ushort offset of z2t from z1t base
#define REFINE_THR 8e-5f

typedef __attribute__((ext_vector_type(8))) short bf16x8;
typedef __attribute__((ext_vector_type(4))) float f32x4;
typedef __attribute__((ext_vector_type(8))) ushort u16x8;

__device__ __forceinline__ ushort bf16_rne(float x) {
  unsigned u = __float_as_uint(x);
  return (ushort)((u + 0x7FFFu + ((u >> 16) & 1u)) >> 16);
}
__device__ __forceinline__ float bf16f(ushort h) {
  return __uint_as_float(((unsigned)h) << 16);
}
__device__ __forceinline__ void gld16(void* l, const void* g) {
  __builtin_amdgcn_global_load_lds(
      (const __attribute__((address_space(1))) unsigned int*)g,
      (__attribute__((address_space(3))) unsigned int*)l, 16, 0, 0);
}

// ---------------- A: prep. blocks 0..1023 = z (rt,quarter), 1024..1027 = e --
__global__ __launch_bounds__(256) void k_prep(const float* __restrict__ z,
                                              const float* __restrict__ emb,
                                              ushort* __restrict__ zt,
                                              float* __restrict__ ws,
                                              float* __restrict__ out) {
  __shared__ float lt[64][132];
  __shared__ float sq[128];
  const int tid = threadIdx.x;
  if (blockIdx.x >= 1024) {
    const int k = (blockIdx.x - 1024) * 256 + tid;   // 0..1023
    if (k == 0) { out[LOSS_OFF] = 0.0f; ((int*)ws)[WS_CNT] = 0; }
    const int ct = k >> 8, n = k & 255;
    const float* er = emb + k * DDIM;
    ushort* e1t = (ushort*)(ws + WS_E1);
    ushort* e2t = (ushort*)(ws + WS_E2);
    float bsum = 0.f;
    for (int s = 0; s < 8; ++s) {
#pragma unroll
      for (int kq = 0; kq < 4; ++kq) {
        const float4 v0 = *(const float4*)(er + s * 32 + kq * 8);
        const float4 v1 = *(const float4*)(er + s * 32 + kq * 8 + 4);
        const float v[8] = {v0.x, v0.y, v0.z, v0.w, v1.x, v1.y, v1.z, v1.w};
        u16x8 h, l;
#pragma unroll
        for (int j = 0; j < 8; ++j) {
          bsum = fmaf(v[j], v[j], bsum);
          h[j] = bf16_rne(v[j]);
          l[j] = bf16_rne(v[j] - bf16f(h[j]));
        }
        const int off = ct * 65536 + s * 8192 + kq * 2048 + n * 8;
        *(u16x8*)(e1t + off) = h;
        *(u16x8*)(e2t + off) = l;
      }
    }
    ws[WS_B + k] = bsum;
    return;
  }
  const int rt = blockIdx.x >> 2;
  const int qp = blockIdx.x & 3;
  const int b = rt >> 3;
  const int hw0 = (rt & 7) << 7;
  ushort* z1t = zt;
  ushort* z2t = zt + Z2T_OFF;
  const int m = tid & 127, half = tid >> 7;
  const int lc = tid >> 2, lq = tid & 3;
  float as[4] = {0.f, 0.f, 0.f, 0.f};
  {
    const float* src = z + b * 262144 + ((qp << 6) + lc) * 1024 + hw0 + (lq << 5);
#pragma unroll
    for (int i = 0; i < 8; ++i)
      *(float4*)&lt[lc][(lq << 5) + (i << 2)] = *(const float4*)(src + (i << 2));
    __syncthreads();
    const int s = (qp << 1) + half;
#pragma unroll
    for (int kq = 0; kq < 4; ++kq) {
      u16x8 h, l;
#pragma unroll
      for (int j = 0; j < 8; ++j) {
        const float v = lt[(half << 5) + (kq << 3) + j][m];
        as[j & 3] = fmaf(v, v, as[j & 3]);
        h[j] = bf16_rne(v);
        l[j] = bf16_rne(v - bf16f(h[j]));
      }
      const int off = rt * 32768 + ((s << 2) + kq) * 1024 + (m << 3);
      *(u16x8*)(z1t + off) = h;
      *(u16x8*)(z2t + off) = l;
    }
    __syncthreads();
  }
  const float asum = (as[0] + as[1]) + (as[2] + as[3]);
  if (half) sq[m] = asum;
  __syncthreads();
  if (!half) ws[WS_A + qp * 32768 + rt * 128 + m] = asum + sq[m];
}

// ---------------- B: MFMA score — BM=64, early e-issue, 2 blocks/CU ---------
// 512 thr (8 waves 2x4; wave = 32 rows x 64 cols), 4 ct-strips x 8 K-steps.
// z dbuf 16 KB via gld16 (vmcnt(1) ledger); e fragments from L2, issued right
// after barrier 1 so ds_read+lgkm+barrier2 cover their latency. Grid 512.
__global__ __launch_bounds__(512, 4) void k_score(const ushort* __restrict__ zt,
                                                  const float* __restrict__ emb,
                                                  float* out,
                                                  float* __restrict__ ws,
                                                  int fused) {
  __shared__ __align__(16) char smem[33312];
  ushort* zl = (ushort*)smem;                 // dbuf 2 x 4096 ushorts (16 KB)
  float* Bs = (float*)(smem + 16384);         // 1024 f
  float* pvs = (float*)(smem + 20480);        // [16][64]
  float* sm2 = (float*)(smem + 33024);        // 8 f
  int* idxs = (int*)(smem + 33056);           // 64 ints
  const int tid = threadIdx.x;
  const int bid = blockIdx.x;                 // 0..511
  const int rt = ((bid >> 4) << 3) | (bid & 7);    // pair halves share an XCD
  const int mh = ((bid >> 3) & 1) << 6;            // m-half within rt tile
  const int row0 = (rt << 7) + mh;                 // 64 rows
  const ushort* z1t = zt;
  const ushort* z2t = zt + Z2T_OFF;
  const ushort* e1t = (const ushort*)(ws + WS_E1);
  const ushort* e2t = (const ushort*)(ws + WS_E2);
  const int w = tid >> 6, L = tid & 63;
  const int l15 = L & 15, kq = L >> 4;
  const int wr = w >> 2, wc = w & 3;          // 2 x 4 wave grid

  Bs[tid] = ws[WS_B + tid];
  Bs[tid + 512] = ws[WS_B + tid + 512];
  float Av[2][4];
#pragma unroll
  for (int mi = 0; mi < 2; ++mi) {
    const int base = row0 + (wr << 5) + (mi << 4) + (kq << 2);
    const float4 a0 = *(const float4*)(ws + WS_A + base);
    const float4 a1 = *(const float4*)(ws + WS_A + 32768 + base);
    const float4 a2 = *(const float4*)(ws + WS_A + 65536 + base);
    const float4 a3 = *(const float4*)(ws + WS_A + 98304 + base);
    Av[mi][0] = (a0.x + a1.x) + (a2.x + a3.x);
    Av[mi][1] = (a0.y + a1.y) + (a2.y + a3.y);
    Av[mi][2] = (a0.z + a1.z) + (a2.z + a3.z);
    Av[mi][3] = (a0.w + a1.w) + (a2.w + a3.w);
  }
  asm volatile("s_waitcnt vmcnt(0)" ::: "memory");
  __builtin_amdgcn_sched_barrier(0);
  __syncthreads();

  // z staging: wave w owns one 1KB slab per step: kq=w&3, array z1 (w<4)/z2
  const ushort* zsrc = (w < 4 ? z1t : z2t) + rt * 32768 + ((w & 3) << 10)
                       + (mh << 3) + (L << 3);
  ushort* zdst0 = zl + ((w & 3) << 9) + ((w >> 2) << 11);
  auto stage = [&](int q, int bf) {
    gld16(zdst0 + (bf << 12), zsrc + ((q & 7) << 12));
  };
  // e fragment addressing (global, fragment-ordered)
  const int ebase_th = (kq << 11) + (((wc << 6) + l15) << 3);

  f32x4 acc[2][4];
  float v1[2][4], v2[2][4];
  int i1[2][4];
#pragma unroll
  for (int mi = 0; mi < 2; ++mi)
#pragma unroll
    for (int r = 0; r < 4; ++r) {
      acc[mi][r] = (f32x4){0.f, 0.f, 0.f, 0.f};
      v1[mi][r] = 3.0e38f; v2[mi][r] = 3.0e38f; i1[mi][r] = 0;
    }

  stage(0, 0);
  stage(1, 1);

  auto body = [&](int q, int cur, bool last) {
    if (!last) asm volatile("s_waitcnt vmcnt(1)" ::: "memory");
    else       asm volatile("s_waitcnt vmcnt(0)" ::: "memory");
    __builtin_amdgcn_sched_barrier(0);
    __builtin_amdgcn_s_barrier();
    __builtin_amdgcn_sched_barrier(0);
    // e fragments issued EARLY (no LDS dependency): latency covered by the
    // ds_reads + lgkmcnt + barrier below; consumed by this step's MFMA via
    // the compiler's own data-dep wait.
    bf16x8 b1[4], b2[4];
    {
      const int ct = q >> 3, s = q & 7;
      const ushort* e1p = e1t + (ct << 16) + (s << 13) + ebase_th;
      const ushort* e2p = e2t + (ct << 16) + (s << 13) + ebase_th;
#pragma unroll
      for (int nj = 0; nj < 4; ++nj) {
        b1[nj] = *(const bf16x8*)(e1p + (nj << 7));
        b2[nj] = *(const bf16x8*)(e2p + (nj << 7));
      }
    }
    const ushort* lb = zl + (cur << 12);
    bf16x8 a1[2], a2[2];
#pragma unroll
    for (int mi = 0; mi < 2; ++mi) {
      const int off = (kq << 9) + (((wr << 5) + (mi << 4) + l15) << 3);
      a1[mi] = *(const bf16x8*)&lb[off];
      a2[mi] = *(const bf16x8*)&lb[2048 + off];
    }
    asm volatile("s_waitcnt lgkmcnt(0)" ::: "memory");
    __builtin_amdgcn_sched_barrier(0);
    __builtin_amdgcn_s_barrier();
    __builtin_amdgcn_sched_barrier(0);
    if (q < 30) stage(q + 2, cur);
    __builtin_amdgcn_s_setprio(1);
#pragma unroll
    for (int mi = 0; mi < 2; ++mi)
#pragma unroll
      for (int nj = 0; nj < 4; ++nj) {
        acc[mi][nj] = __builtin_amdgcn_mfma_f32_16x16x32_bf16(a2[mi], b1[nj], acc[mi][nj], 0, 0, 0);
        acc[mi][nj] = __builtin_amdgcn_mfma_f32_16x16x32_bf16(a1[mi], b2[nj], acc[mi][nj], 0, 0, 0);
        acc[mi][nj] = __builtin_amdgcn_mfma_f32_16x16x32_bf16(a1[mi], b1[nj], acc[mi][nj], 0, 0, 0);
      }
    __builtin_amdgcn_s_setprio(0);
    if ((q & 7) == 7) {   // strip boundary: fold scores + chunk minima
      const int ct = q >> 3;
      float bb[4];
#pragma unroll
      for (int nj = 0; nj < 4; ++nj)
        bb[nj] = Bs[(ct << 8) + (wc << 6) + (nj << 4) + l15];
      float cm[2][4];
#pragma unroll
      for (int mi = 0; mi < 2; ++mi)
#pragma unroll
        for (int r = 0; r < 4; ++r) cm[mi][r] = 3.0e38f;
#pragma unroll
      for (int mi = 0; mi < 2; ++mi)
#pragma unroll
        for (int nj = 0; nj < 4; ++nj) {
          const int kg = (ct << 8) + (wc << 6) + (nj << 4) + l15;
#pragma unroll
          for (int r = 0; r < 4; ++r) {
            const float sc = fmaf(-2.0f, acc[mi][nj][r], Av[mi][r] + bb[nj]);
            if (sc < v1[mi][r]) { v2[mi][r] = v1[mi][r]; v1[mi][r] = sc; i1[mi][r] = kg; }
            else if (sc < v2[mi][r]) v2[mi][r] = sc;
            cm[mi][r] = fminf(cm[mi][r], sc);
          }
          acc[mi][nj] = (f32x4){0.f, 0.f, 0.f, 0.f};
        }
#pragma unroll
      for (int mi = 0; mi < 2; ++mi)
#pragma unroll
        for (int r = 0; r < 4; ++r) {
          float cv = cm[mi][r];
#pragma unroll
          for (int o = 1; o < 16; o <<= 1) cv = fminf(cv, __shfl_xor(cv, o));
          if (l15 == 0) {
            const int rowl = (wr << 5) + (mi << 4) + (kq << 2) + r;
            pvs[((ct << 2) | wc) * 64 + rowl] = cv;
          }
        }
    }
  };

  for (int q = 0; q < 31; ++q) body(q, q & 1, false);
  body(31, 1, true);

  // cross-l15 reduce of global top-2
#pragma unroll
  for (int mi = 0; mi < 2; ++mi)
#pragma unroll
    for (int r = 0; r < 4; ++r) {
      float a = v1[mi][r], bb = v2[mi][r];
      int ii = i1[mi][r];
#pragma unroll
      for (int o = 1; o < 16; o <<= 1) {
        const float oa = __shfl_xor(a, o);
        const float ob = __shfl_xor(bb, o);
        const int oi = __shfl_xor(ii, o);
        bb = fminf(fminf(bb, ob), fmaxf(a, oa));
        if (oa < a || (oa == a && oi < ii)) { a = oa; ii = oi; }
      }
      v1[mi][r] = a; v2[mi][r] = bb; i1[mi][r] = ii;
    }

  __syncthreads();
  // flush chunk minima to ws
  for (int i = tid; i < 1024; i += 512) {
    const int c = i >> 6, rl = i & 63;
    ws[WS_PV + (c << 15) + row0 + rl] = pvs[i];
  }
  float* red = (float*)smem;   // [4 wc][64 rows][3] = 3 KB (z dbuf dead)
  if (l15 == 0) {
#pragma unroll
    for (int mi = 0; mi < 2; ++mi)
#pragma unroll
      for (int r = 0; r < 4; ++r) {
        const int rl = (wr << 5) + (mi << 4) + (kq << 2) + r;
        const int b3 = (wc * 64 + rl) * 3;
        red[b3] = v1[mi][r];
        red[b3 + 1] = v2[mi][r];
        red[b3 + 2] = (float)i1[mi][r];
      }
  }
  __syncthreads();
  float losss = 0.f;
  if (tid < 64) {
    float fv1 = 3.0e38f, fv2 = 3.0e38f;
    int fi = 0;
#pragma unroll
    for (int c = 0; c < 4; ++c) {
      const int b3 = (c * 64 + tid) * 3;
      const float a1 = red[b3], a2 = red[b3 + 1];
      const int ai = (int)red[b3 + 2];
      if (a1 < fv1 || (a1 == fv1 && ai < fi)) { fv2 = fminf(fv1, a2); fv1 = a1; fi = ai; }
      else fv2 = fminf(fv2, a1);
    }
    const int row = row0 + tid;
    out[IDX_OFF + row] = (float)fi;
    idxs[tid] = fi;
    if (fv2 - fv1 < REFINE_THR) {
      const int slot = atomicAdd((int*)ws + WS_CNT, 1);
      ((int*)ws)[WS_LIST + slot] = row;
    }
    losss = fv1;
  }
#pragma unroll
  for (int o = 32; o; o >>= 1) losss += __shfl_down(losss, o);
  if ((tid & 63) == 0) sm2[tid >> 6] = losss;
  __syncthreads();
  if (tid == 0) {
    float t = 0.f;
#pragma unroll
    for (int i = 0; i < 8; ++i) t += sm2[i];
    atomicAdd(out + LOSS_OFF, t * (1.25f / 8388608.0f));
  }

  // ---- fused tail: z_q via LDS transpose, 2 col-half passes ----
  if (fused) {
    float* lt2 = (float*)smem;   // [64][129] f32 = 33024 B
    const int b = row0 >> 10;
    const int hw0 = row0 & 1023;
    for (int ch = 0; ch < 2; ++ch) {
      __syncthreads();
      {
        const int r = tid >> 3, seg = tid & 7;
        const float* er = emb + idxs[r] * DDIM + (ch << 7);
        float* dst = lt2 + r * 129;
#pragma unroll
        for (int i = 0; i < 4; ++i) {
          const int c = (seg << 2) + (i << 5);
          const float4 v = *(const float4*)(er + c);
          dst[c] = v.x; dst[c + 1] = v.y; dst[c + 2] = v.z; dst[c + 3] = v.w;
        }
      }
      __syncthreads();
      {
        const int c = tid >> 2;
        const int r0 = (tid & 3) << 4;
        float* dsto = out + b * 262144 + ((ch << 7) + c) * 1024 + hw0 + r0;
#pragma unroll
        for (int i = 0; i < 16; i += 4) {
          float4 v;
          v.x = lt2[(r0 + i + 0) * 129 + c];
          v.y = lt2[(r0 + i + 1) * 129 + c];
          v.z = lt2[(r0 + i + 2) * 129 + c];
          v.w = lt2[(r0 + i + 3) * 129 + c];
          *(float4*)(dsto + i) = v;
        }
      }
    }
  }
}

// ---------------- B3: exact re-solve, candidate chunks, grid-stride ---------
__global__ __launch_bounds__(256) void k_refine(const float* __restrict__ z,
                                                const float* __restrict__ emb,
                                                const float* __restrict__ ws,
                                                float* __restrict__ out,
                                                int fused) {
  __shared__ float zs[4][256];
  const int tid = threadIdx.x;
  const int w = tid >> 6, L = tid & 63;
  const int wg = blockIdx.x * 4 + w;
  const int cnt = ((const int*)ws)[WS_CNT];
  for (int e = wg; e < cnt; e += 1024) {
    const int row = ((const int*)ws)[WS_LIST + e];
    const int b = row >> 10, hw = row & 1023;
#pragma unroll
    for (int q = 0; q < 4; ++q)
      zs[w][(q << 6) + L] = z[b * 262144 + (((q << 6) + L) << 10) + hw];
    asm volatile("s_waitcnt lgkmcnt(0)" ::: "memory");
    float v1c = (L < 16) ? ws[WS_PV + (L << 15) + row] : 3.0e38f;
    float v1 = v1c;
#pragma unroll
    for (int o = 1; o < 64; o <<= 1) v1 = fminf(v1, __shfl_xor(v1, o));
    const float A = (ws[WS_A + row] + ws[WS_A + 32768 + row]) +
                    (ws[WS_A + 65536 + row] + ws[WS_A + 98304 + row]);
    float bv = 3.0e38f;
    int bk = 0;
    for (int tc = 0; tc < 16; ++tc) {
      const float bc = __shfl(v1c, tc);
      if (bc <= v1 + REFINE_THR) {
        const int k = (tc << 6) + L;
        const float* er = emb + k * DDIM;
        float s = 0.f;
        for (int d = 0; d < DDIM; ++d) s = fmaf(zs[w][d], er[d], s);  // R3 chain
        const float sc = fmaf(-2.0f, s, A + ws[WS_B + k]);
        if (sc < bv) { bv = sc; bk = k; }
      }
    }
#pragma unroll
    for (int o = 1; o < 64; o <<= 1) {
      const float ov = __shfl_xor(bv, o);
      const int ok = __shfl_xor(bk, o);
      if (ov < bv || (ov == bv && ok < bk)) { bv = ov; bk = ok; }
    }
    if (L == 0) out[IDX_OFF + row] = (float)bk;
    if (fused) {
#pragma unroll
      for (int ci = 0; ci < 4; ++ci) {
        const int c = (ci << 6) + L;
        out[b * 262144 + c * 1024 + hw] = emb[bk * DDIM + c];
      }
    }
  }
}

// ---------------- C: z_q gather (legacy path only) ----------------
__global__ __launch_bounds__(256) void k_gather(const float* __restrict__ emb,
                                                float* __restrict__ out) {
  const int tid = threadIdx.x;
  const int e0 = (blockIdx.x * 256 + tid) * 16;
  const int b = e0 >> 18;
  const int c = (e0 >> 10) & 255;
  const int n0 = (b << 10) + (e0 & 1023);
#pragma unroll
  for (int g = 0; g < 4; ++g) {
    float q[4];
#pragma unroll
    for (int j = 0; j < 4; ++j) {
      const int id = (int)(out[IDX_OFF + n0 + g * 4 + j] + 0.5f);
      q[j] = emb[id * DDIM + c];
    }
    const float4 qv = {q[0], q[1], q[2], q[3]};
    *(float4*)(out + e0 + g * 4) = qv;
  }
}

extern "C" void kernel_launch(void* const* d_in, const int* in_sizes, int n_in,
                              void* d_out, int out_size, void* d_ws, size_t ws_size,
                              hipStream_t stream) {
  const float* z = (const float*)d_in[0];
  const float* emb = (const float*)d_in[1];
  float* out = (float*)d_out;
  float* ws = (float*)d_ws;
  const int fused = (ws_size >= WS_FUSED_BYTES) ? 1 : 0;
  ushort* zt = fused ? (ushort*)(ws + WS_Z1T) : (ushort*)out;

  k_prep<<<1028, 256, 0, stream>>>(z, emb, zt, ws, out);
  k_score<<<512, 512, 0, stream>>>(zt, emb, out, ws, fused);
  k_refine<<<256, 256, 0, stream>>>(z, emb, ws, out, fused);
  if (!fused) k_gather<<<2048, 256, 0, stream>>>(emb, out);
}